// Round 3
// baseline (473.908 us; speedup 1.0000x reference)
//
#include <hip/hip_runtime.h>
#include <math.h>

#define TOKENS 16384
#define EMBD   4096
#define NEXP   64
#define TOPK   8
#define KSPLIT 8
#define KSLICE (EMBD / KSPLIT)   /* 512 */
#define CHUNK  16
#define EQTR   16                /* experts per wave (64 split across 4 waves) */

// ---------------------------------------------------------------------------
// Kernel 1: transpose W[64][4096] -> Wt[4096][64] so that for a fixed k the
// expert weights are contiguous (enables s_load scalar loads in the GEMM).
// ---------------------------------------------------------------------------
__global__ void transpose_w(const float* __restrict__ W, float* __restrict__ Wt) {
    int idx = blockIdx.x * blockDim.x + threadIdx.x;  // idx = e*4096 + k
    int e = idx >> 12;
    int k = idx & 4095;
    Wt[k * NEXP + e] = W[idx];
}

// ---------------------------------------------------------------------------
// Kernel 2: partial GEMM. lane = token; each wave handles a QUARTER of the
// experts (16). Round-2 post-mortem: VALU busy-time (72 us) == issued work,
// stalled 56% -- grid-limited to 4 waves/SIMD and x loaded right before use.
// Quarter split doubles wave count (8192 -> 5+/SIMD at ~96 VGPR) and the
// chunk loop software-pipelines x: chunk k+1's float4s are loaded before
// chunk k's FMAs, putting ~660 VALU cycles between issue and use.
// The 4 waves of a block read the SAME x rows -> HBM once, L1/L2 after
// (round 2 measured FETCH 225 MB < 2x256 MB for the pair version).
// Numerics: per-(token,expert) FMA chain, chunk boundaries, and f64 outer
// accumulation are untouched -> logits BIT-IDENTICAL to the passing version.
// Grid: (TOKENS/64) x KSPLIT = 2048 blocks of 256.
// ---------------------------------------------------------------------------
__global__ __launch_bounds__(256, 4) void gemm_partial(
    const float* __restrict__ x, const float* __restrict__ Wt,
    float* __restrict__ part) {
    const int lane = threadIdx.x & 63;
    const int wave = threadIdx.x >> 6;
    // expert quarter: wave-uniform in fact, but threadIdx-derived -> hoist to
    // SGPR so the W loads stay scalar (s_load) instead of per-lane vector.
    const int qtr  = __builtin_amdgcn_readfirstlane(wave);
    const int tok  = blockIdx.x * 64 + lane;
    const int ks   = blockIdx.y;
    const int kbase = ks * KSLICE;

    const float* xrow  = x + (size_t)tok * EMBD + kbase;
    const float* wbase = Wt + (size_t)kbase * NEXP + qtr * EQTR;  // wave-uniform

    double accd[EQTR];
#pragma unroll
    for (int e = 0; e < EQTR; ++e) accd[e] = 0.0;

    // prefetch chunk 0
    float4 n0, n1, n2, n3;
    {
        const float4* xp = (const float4*)xrow;
        n0 = xp[0]; n1 = xp[1]; n2 = xp[2]; n3 = xp[3];
    }

#pragma unroll 2
    for (int kc = 0; kc < KSLICE; kc += CHUNK) {
        float4 a = n0, b = n1, c = n2, d4 = n3;
        // issue next chunk's loads before this chunk's FMAs (last iter
        // harmlessly re-reads kc=0: in-bounds, L1-hot)
        const int kcn = (kc + CHUNK < KSLICE) ? kc + CHUNK : 0;
        const float4* xp = (const float4*)(xrow + kcn);
        n0 = xp[0]; n1 = xp[1]; n2 = xp[2]; n3 = xp[3];

        float xv[CHUNK] = {a.x, a.y, a.z, a.w,  b.x, b.y, b.z, b.w,
                           c.x, c.y, c.z, c.w,  d4.x, d4.y, d4.z, d4.w};

        float accf[EQTR];
#pragma unroll
        for (int e = 0; e < EQTR; ++e) accf[e] = 0.0f;

#pragma unroll
        for (int j = 0; j < CHUNK; ++j) {
            const float xj = xv[j];
            const float* wrow = wbase + (size_t)(kc + j) * NEXP;  // wave-uniform
#pragma unroll
            for (int e = 0; e < EQTR; ++e)
                accf[e] = fmaf(wrow[e], xj, accf[e]);
        }

#pragma unroll
        for (int e = 0; e < EQTR; ++e) accd[e] += (double)accf[e];
    }

    float4* dst = (float4*)(part + ((size_t)ks * TOKENS + tok) * NEXP
                            + (size_t)qtr * EQTR);
#pragma unroll
    for (int v = 0; v < EQTR / 4; ++v)
        dst[v] = make_float4((float)accd[4 * v],     (float)accd[4 * v + 1],
                             (float)accd[4 * v + 2], (float)accd[4 * v + 3]);
}

// ---------------------------------------------------------------------------
// Kernel 3: reduce K-split partials (fixed order f64 -> logits bit-identical),
// RANK-BASED top-8 (ties -> lower index, matching jax.lax.top_k), masked
// softmax. One wave per token, 4 tokens per block.
// ---------------------------------------------------------------------------
__global__ __launch_bounds__(256) void topk_softmax(
    const float* __restrict__ part, float* __restrict__ probs,
    float* __restrict__ idxout) {
    __shared__ float lval[4][NEXP];
    __shared__ float lidx[4][TOPK];

    const int lane = threadIdx.x & 63;   // = expert
    const int wave = threadIdx.x >> 6;
    const int tok  = blockIdx.x * 4 + wave;

    double d = 0.0;
#pragma unroll
    for (int s = 0; s < KSPLIT; ++s)
        d += (double)part[((size_t)s * TOKENS + tok) * NEXP + lane];
    const float logit = (float)d;

    lval[wave][lane] = logit;
    __syncthreads();

    // rank = #{j : v_j > v_lane} + #{j : v_j == v_lane && j < lane}
    const float4* lv4 = (const float4*)lval[wave];  // broadcast reads
    int rank = 0;
    float m = -INFINITY;
#pragma unroll
    for (int q4 = 0; q4 < NEXP / 4; ++q4) {
        float4 v = lv4[q4];
        const int qb = q4 * 4;
        rank += (v.x > logit || (v.x == logit && qb + 0 < lane)) ? 1 : 0;
        rank += (v.y > logit || (v.y == logit && qb + 1 < lane)) ? 1 : 0;
        rank += (v.z > logit || (v.z == logit && qb + 2 < lane)) ? 1 : 0;
        rank += (v.w > logit || (v.w == logit && qb + 3 < lane)) ? 1 : 0;
        m = fmaxf(fmaxf(m, v.x), fmaxf(v.y, fmaxf(v.z, v.w)));
    }

    const bool sel = rank < TOPK;
    const float t  = sel ? expf(logit - m) : 0.0f;

    float denom = t;
#pragma unroll
    for (int off = 32; off > 0; off >>= 1)
        denom += __shfl_xor(denom, off);

    if (sel) lidx[wave][rank] = (float)lane;   // scatter index by rank
    __syncthreads();

    probs[(size_t)tok * NEXP + lane] = sel ? (t / denom) : 0.0f;
    if (lane < TOPK) idxout[(size_t)tok * TOPK + lane] = lidx[wave][lane];
}

// ---------------------------------------------------------------------------
extern "C" void kernel_launch(void* const* d_in, const int* in_sizes, int n_in,
                              void* d_out, int out_size, void* d_ws, size_t ws_size,
                              hipStream_t stream) {
    const float* x = (const float*)d_in[0];   // [4,4096,4096]
    const float* W = (const float*)d_in[1];   // [64,4096]

    float* out    = (float*)d_out;
    float* probs  = out;                         // 16384*64 floats
    float* idxout = out + (size_t)TOKENS * NEXP; // 16384*8 floats (indices as float)

    float* Wt   = (float*)d_ws;                  // 4096*64 floats = 1 MB
    float* part = Wt + (size_t)EMBD * NEXP;      // 8*16384*64 floats = 32 MB

    hipLaunchKernelGGL(transpose_w, dim3((EMBD * NEXP) / 256), dim3(256), 0, stream,
                       W, Wt);
    hipLaunchKernelGGL(gemm_partial, dim3(TOKENS / 64, KSPLIT), dim3(256), 0, stream,
                       x, Wt, part);
    hipLaunchKernelGGL(topk_softmax, dim3(TOKENS / 4), dim3(256), 0, stream,
                       part, probs, idxout);
}